// Round 1
// 826.478 us; speedup vs baseline: 1.0306x; 1.0306x over previous
//
#include <hip/hip_runtime.h>

// FFM pairwise interaction:
//   out[b, p, e] = x[b,i,e] * x[b,j,e] * fe[i,j,e] * fe[j,i,e]
// for pairs p=(i,j), i<j in row-major triu order. B=4096, F=40, E=64, P=780.
//
// V2 strategy (theory: kernel ~330us vs 140us write-roofline):
//  * Precompute inter[p,e] = fe[i,j,e]*fe[j,i,e] (195 KB) + packed pair table
//    into workspace with a tiny kernel -> halves hot-loop VMEM loads, matches
//    reference rounding order (xi*xj)*(fij*fji) exactly.
//  * Non-temporal stores for the 818 MB output stream -> no L2 allocation,
//    keeps inter/x cache-resident (fill kernels hit 6.25 TB/s on this path).
//  * Strength-reduced addressing: out/inter share index o advancing by +256/iter.

#define NF  40
#define NE  64
#define NP  780          // NF*(NF-1)/2
#define NE4 16           // float4 per embedding row
#define NPG 195          // NP/4 pair-groups (4 pairs per wave-iteration)

typedef float f4v __attribute__((ext_vector_type(4)));

// ---------------------------------------------------------------------------
// Kernel 1: precompute inter[p, e] and packed (i<<8|j) pair table. ~5 us.
// One float4 per thread: idx in [0, NP*NE4).
__global__ __launch_bounds__(256) void ffm_pre(
    const float* __restrict__ fe,
    float* __restrict__ inter,
    int* __restrict__ pij)
{
    const int idx = blockIdx.x * 256 + threadIdx.x;
    if (idx >= NP * NE4) return;
    const int p  = idx >> 4;
    const int e4 = idx & 15;

    // decode pair p -> (i, j), i<j, row-major triu order
    int i = 0, base = 0;
    while (p >= base + (NF - 1 - i)) { base += NF - 1 - i; ++i; }
    const int j = i + 1 + (p - base);

    if (e4 == 0) pij[p] = (i << 8) | j;

    const float4 fij = ((const float4*)fe)[(i * NF + j) * NE4 + e4];
    const float4 fji = ((const float4*)fe)[(j * NF + i) * NE4 + e4];
    float4 r;
    r.x = fij.x * fji.x;
    r.y = fij.y * fji.y;
    r.z = fij.z * fji.z;
    r.w = fij.w * fji.w;
    ((float4*)inter)[idx] = r;
}

// ---------------------------------------------------------------------------
// Kernel 2: main. 1 block per batch row. x row staged in LDS, inter via L2
// (195 KB, cache-resident), nt float4 stores.
__global__ __launch_bounds__(256) void ffm_main(
    const float* __restrict__ x,
    const float* __restrict__ inter,
    const int* __restrict__ pij_g,
    float* __restrict__ out)
{
    __shared__ float xs[NF * NE];   // 10 KB: x[b, :, :]
    __shared__ int   pij[NP];       // 3.1 KB

    const int tid = threadIdx.x;
    const int b   = blockIdx.x;

    // coalesced loads of pair table + x row
    for (int idx = tid; idx < NP; idx += 256) pij[idx] = pij_g[idx];

    const float4* xb4 = (const float4*)(x + (size_t)b * (NF * NE));
    float4* xs4 = (float4*)xs;
    for (int idx = tid; idx < NF * NE / 4; idx += 256) xs4[idx] = xb4[idx];

    __syncthreads();

    const int lane = tid & 63;
    const int wave = tid >> 6;
    const int e4   = lane & 15;     // which float4 of the 16 covering E=64

    const f4v* in4 = (const f4v*)inter;
    f4v* ob4 = (f4v*)out + (size_t)b * (size_t)(NP * NE4);
    const float4* xs4c = (const float4*)xs;

    // o = p*16 + e4 in float4 units; per wave: start = wave*64 + lane, step 256.
    // Wave stores 64 consecutive float4 (1 KB contiguous) per iteration.
    int o = wave * 64 + lane;
    #pragma unroll 2
    for (int g = wave; g < NPG; g += 4, o += 256) {
        const int p  = o >> 4;
        const int pk = pij[p];
        const int i  = pk >> 8;
        const int j  = pk & 255;

        const float4 xi = xs4c[(i << 4) + e4];
        const float4 xj = xs4c[(j << 4) + e4];
        const f4v    iv = in4[o];

        f4v r;
        r.x = (xi.x * xj.x) * iv.x;
        r.y = (xi.y * xj.y) * iv.y;
        r.z = (xi.z * xj.z) * iv.z;
        r.w = (xi.w * xj.w) * iv.w;

        __builtin_nontemporal_store(r, ob4 + o);
    }
}

// ---------------------------------------------------------------------------
// Fallback (ws too small): original single-kernel version, fe read via L2.
__global__ __launch_bounds__(256) void ffm_kernel_fb(
    const float* __restrict__ x,
    const float* __restrict__ fe,
    float* __restrict__ out)
{
    __shared__ float xs[NF * NE];
    __shared__ int   pij[NP];

    const int tid = threadIdx.x;
    const int b   = blockIdx.x;

    if (tid < NF - 1) {
        const int i = tid;
        const int base = i * (2 * NF - i - 1) / 2;
        for (int j = i + 1; j < NF; ++j)
            pij[base + (j - i - 1)] = (i << 8) | j;
    }

    const float4* xb4 = (const float4*)(x + (size_t)b * (NF * NE));
    float4* xs4 = (float4*)xs;
    for (int idx = tid; idx < NF * NE / 4; idx += 256) xs4[idx] = xb4[idx];

    __syncthreads();

    const int wave = tid >> 6;
    const int lane = tid & 63;
    const int e4   = lane & 15;
    const int psub = lane >> 4;

    const float4* fe4 = (const float4*)fe;
    float4* ob4 = (float4*)(out + (size_t)b * (size_t)(NP * NE));

    for (int g = wave; g < NPG; g += 4) {
        const int p = g * 4 + psub;
        const int packed = pij[p];
        const int i = packed >> 8;
        const int j = packed & 255;

        const float4 xi  = xs4[i * 16 + e4];
        const float4 xj  = xs4[j * 16 + e4];
        const float4 fij = fe4[(i * NF + j) * 16 + e4];
        const float4 fji = fe4[(j * NF + i) * 16 + e4];

        float4 r;
        r.x = (xi.x * xj.x) * (fij.x * fji.x);
        r.y = (xi.y * xj.y) * (fij.y * fji.y);
        r.z = (xi.z * xj.z) * (fij.z * fji.z);
        r.w = (xi.w * xj.w) * (fij.w * fji.w);

        ob4[p * 16 + e4] = r;
    }
}

extern "C" void kernel_launch(void* const* d_in, const int* in_sizes, int n_in,
                              void* d_out, int out_size, void* d_ws, size_t ws_size,
                              hipStream_t stream) {
    const float* x  = (const float*)d_in[0];   // [B, 40, 64] fp32
    const float* fe = (const float*)d_in[1];   // [40, 40, 64] fp32
    float* out = (float*)d_out;                // [B, 780*64] fp32

    const int B = in_sizes[0] / (NF * NE);     // 4096

    const size_t inter_bytes = (size_t)NP * NE * sizeof(float);  // 199,680 B
    const size_t pij_bytes   = (size_t)NP * sizeof(int);         //   3,120 B

    if (ws_size >= inter_bytes + pij_bytes) {
        float* inter = (float*)d_ws;
        int*   pij   = (int*)((char*)d_ws + inter_bytes);        // 16B-aligned

        const int pre_blocks = (NP * NE4 + 255) / 256;           // 49
        ffm_pre<<<dim3(pre_blocks), dim3(256), 0, stream>>>(fe, inter, pij);
        ffm_main<<<dim3(B), dim3(256), 0, stream>>>(x, inter, pij, out);
    } else {
        ffm_kernel_fb<<<dim3(B), dim3(256), 0, stream>>>(x, fe, out);
    }
}